// Round 1
// baseline (278.950 us; speedup 1.0000x reference)
//
#include <hip/hip_runtime.h>
#include <math.h>

#define BATCH 64
#define ADIM  1152
#define BDIM  32
#define POSE  16
#define SLICE (BDIM * POSE)          // 512 floats per (batch) capsule-state
#define CHUNKS 18
#define A_PER_CHUNK (ADIM / CHUNKS)  // 64
#define EPSQ 1e-6f

// One pass over v for routing iteration `iter`:
//   b[a,bc] = logits[a,bc] + sum_{j<iter} dot(p_j[bc,:], v[a,bc,:])
//   c[a,:]  = softmax_bc(b[a,:])
//   s[bc,k] += sum_a c[a,bc] * v[a,bc,k]
__global__ __launch_bounds__(256) void route_pass(
    const float* __restrict__ v,       // [BATCH][ADIM][BDIM][POSE]
    const float* __restrict__ logits,  // [ADIM][BDIM]
    const float* __restrict__ p_buf,   // [3][BATCH][BDIM][POSE]
    float* __restrict__ s_out,         // [BATCH][BDIM][POSE] (this iter's slice)
    int iter)
{
    const int bt    = blockIdx.x / CHUNKS;
    const int chunk = blockIdx.x % CHUNKS;
    const int t     = threadIdx.x;
    const int bc    = t & 31;   // capsule (softmax dim)
    const int a_sub = t >> 5;   // 0..7 : 8 'a' rows in flight

    __shared__ float p_sh[2][SLICE];
    __shared__ float red[8 * SLICE];   // 16 KB reduction scratch

    for (int j = 0; j < iter; ++j)
        for (int idx = t; idx < SLICE; idx += 256)
            p_sh[j][idx] = p_buf[(size_t)j * BATCH * SLICE + (size_t)bt * SLICE + idx];
    __syncthreads();

    float acc[POSE];
#pragma unroll
    for (int k = 0; k < POSE; ++k) acc[k] = 0.f;

    const int a0 = chunk * A_PER_CHUNK;
    for (int ai = 0; ai < A_PER_CHUNK / 8; ++ai) {
        const int a = a0 + ai * 8 + a_sub;
        const float4* vp4 = reinterpret_cast<const float4*>(
            v + ((size_t)bt * ADIM + a) * SLICE + bc * POSE);
        float vv[POSE];
#pragma unroll
        for (int q = 0; q < 4; ++q) {
            float4 f = vp4[q];
            vv[q * 4 + 0] = f.x; vv[q * 4 + 1] = f.y;
            vv[q * 4 + 2] = f.z; vv[q * 4 + 3] = f.w;
        }

        float bval = logits[a * BDIM + bc];
        for (int j = 0; j < iter; ++j) {
            float d = 0.f;
#pragma unroll
            for (int k = 0; k < POSE; ++k) d += p_sh[j][bc * POSE + k] * vv[k];
            bval += d;
        }

        // softmax over the 32 capsules (32-lane shuffle groups inside wave64)
        float m = bval;
#pragma unroll
        for (int off = 16; off > 0; off >>= 1)
            m = fmaxf(m, __shfl_xor(m, off, 32));
        float e = __expf(bval - m);
        float ssum = e;
#pragma unroll
        for (int off = 16; off > 0; off >>= 1)
            ssum += __shfl_xor(ssum, off, 32);
        float c = e / ssum;

#pragma unroll
        for (int k = 0; k < POSE; ++k) acc[k] = fmaf(c, vv[k], acc[k]);
    }

    // reduce the 8 a_sub partials in LDS, then one atomicAdd per element
#pragma unroll
    for (int k = 0; k < POSE; ++k) red[a_sub * SLICE + bc * POSE + k] = acc[k];
    __syncthreads();

    for (int idx = t; idx < SLICE; idx += 256) {
        float s = 0.f;
#pragma unroll
        for (int asb = 0; asb < 8; ++asb) s += red[asb * SLICE + idx];
        atomicAdd(&s_out[(size_t)bt * SLICE + idx], s);
    }
}

// squash: norm_sq over the B dim per pose element; last iter also emits outputs
__global__ __launch_bounds__(512) void squash_kernel(
    const float* __restrict__ s_in,   // [BATCH][BDIM][POSE]
    float* __restrict__ p_out,        // [BATCH][BDIM][POSE]
    float* __restrict__ out,          // a_out (8192) ++ p (32768)
    int last)
{
    const int bt = blockIdx.x;
    const int t = threadIdx.x;        // t = bc*16 + pose
    const int pose = t & 15;

    __shared__ float sq[512];
    __shared__ float ns[16];

    float sv = s_in[(size_t)bt * SLICE + t];
    sq[t] = sv * sv;
    __syncthreads();
    if (t < 16) {
        float a = 0.f;
        for (int b2 = 0; b2 < BDIM; ++b2) a += sq[b2 * POSE + t];
        ns[t] = a;
    }
    __syncthreads();
    float n = ns[pose];
    float pv = sqrtf(n + EPSQ) / (1.f + n) * sv;
    p_out[(size_t)bt * SLICE + t] = pv;

    if (last) {
        // p output: (batch, B, 4, 4, 1) flat
        out[8192 + bt * SLICE + t] = pv;
        sq[t] = pv * pv;
        __syncthreads();
        // a_out[bt][bc][p2] = sqrt(sum_p1 p[bc][p1][p2]^2)
        if (t < 128) {
            int b2 = t >> 2, p2 = t & 3;
            float a = 0.f;
#pragma unroll
            for (int p1 = 0; p1 < 4; ++p1) a += sq[b2 * POSE + p1 * 4 + p2];
            out[bt * 128 + b2 * 4 + p2] = sqrtf(a);
        }
    }
}

extern "C" void kernel_launch(void* const* d_in, const int* in_sizes, int n_in,
                              void* d_out, int out_size, void* d_ws, size_t ws_size,
                              hipStream_t stream) {
    const float* v      = (const float*)d_in[1];   // (64,1152,32,4,4,1)
    const float* logits = (const float*)d_in[2];   // (1,1152,32,1,1,1)
    float* out = (float*)d_out;

    // workspace: 3 s-buffers + 3 p-buffers, each [BATCH][SLICE] fp32 (768 KB)
    float* s_buf = (float*)d_ws;
    float* p_buf = s_buf + 3 * BATCH * SLICE;

    hipMemsetAsync(s_buf, 0, (size_t)3 * BATCH * SLICE * sizeof(float), stream);

    for (int it = 0; it < 3; ++it) {
        route_pass<<<dim3(BATCH * CHUNKS), dim3(256), 0, stream>>>(
            v, logits, p_buf, s_buf + (size_t)it * BATCH * SLICE, it);
        squash_kernel<<<dim3(BATCH), dim3(512), 0, stream>>>(
            s_buf + (size_t)it * BATCH * SLICE,
            p_buf + (size_t)it * BATCH * SLICE,
            out, it == 2 ? 1 : 0);
    }
}